// Round 3
// baseline (527.938 us; speedup 1.0000x reference)
//
#include <hip/hip_runtime.h>

// GNN27: two-branch diffusion GCN (N=8192, F_IN=11, F1=16, F2=32) + multi-head
// tanh-attention pooling. All fp32. Memory-bound on the two 268MB adjacencies,
// each streamed twice (layer1, layer2) -> 1.07GB HBM floor ~170us.
//
// R1: 256B-granular direct loads -> 680 GB/s. R2: LDS staging + __syncthreads
// dbuf -> 955 GB/s; vmcnt in-order retire means every P-load wait drained the
// just-issued next-tile stage (serialized pipeline). R3: barrier-free per-wave
// pipeline — each wave stages AND consumes its own 8 rows; all P-loads for a
// tile are issued BEFORE the next stage so counted waits never retire it;
// single vmcnt(0) rendezvous per tile against a stage issued one full tile ago.

constexpr int N = 8192;

#define GLOBAL_AS __attribute__((address_space(1)))
#define LDS_AS __attribute__((address_space(3)))

__device__ __forceinline__ void gload_lds16(const float* g, float* l) {
    __builtin_amdgcn_global_load_lds((const GLOBAL_AS void*)g, (LDS_AS void*)l, 16, 0, 0);
}

// ---------------- kernel 1: P1 = x @ W1   ([N,11] @ [11,16]) ----------------
__global__ void k_dense_in(const float* __restrict__ x0, const float* __restrict__ x1,
                           const float* __restrict__ W0, const float* __restrict__ W1,
                           float* __restrict__ o0, float* __restrict__ o1) {
    const int branch = blockIdx.y;
    const float* __restrict__ x = branch ? x1 : x0;
    const float* __restrict__ W = branch ? W1 : W0;
    float* __restrict__ o = branch ? o1 : o0;
    __shared__ float sW[11 * 16];
    if (threadIdx.x < 176) sW[threadIdx.x] = W[threadIdx.x];
    __syncthreads();
    const int n = blockIdx.x * blockDim.x + threadIdx.x;  // grid.x*256 == N exactly
    float xr[11];
#pragma unroll
    for (int j = 0; j < 11; ++j) xr[j] = x[n * 11 + j];
    float acc[16];
#pragma unroll
    for (int f = 0; f < 16; ++f) acc[f] = 0.f;
#pragma unroll
    for (int j = 0; j < 11; ++j)
#pragma unroll
        for (int f = 0; f < 16; ++f) acc[f] += xr[j] * sW[j * 16 + f];
#pragma unroll
    for (int q = 0; q < 4; ++q) {
        float4 r = make_float4(acc[q * 4 + 0], acc[q * 4 + 1], acc[q * 4 + 2], acc[q * 4 + 3]);
        *reinterpret_cast<float4*>(&o[n * 16 + q * 4]) = r;
    }
}

// ---------------- kernel 3: P2 = H1 @ W2   ([N,16] @ [16,32]) ----------------
__global__ void k_dense_mid(const float* __restrict__ h0, const float* __restrict__ h1,
                            const float* __restrict__ W0, const float* __restrict__ W1,
                            float* __restrict__ o0, float* __restrict__ o1) {
    const int branch = blockIdx.y;
    const float* __restrict__ h = branch ? h1 : h0;
    const float* __restrict__ W = branch ? W1 : W0;
    float* __restrict__ o = branch ? o1 : o0;
    __shared__ float sW[16 * 32];
    for (int i = threadIdx.x; i < 512; i += blockDim.x) sW[i] = W[i];
    __syncthreads();
    const int n = blockIdx.x * blockDim.x + threadIdx.x;
    float hr[16];
#pragma unroll
    for (int q = 0; q < 4; ++q)
        *reinterpret_cast<float4*>(&hr[q * 4]) =
            *reinterpret_cast<const float4*>(&h[n * 16 + q * 4]);
    float acc[32];
#pragma unroll
    for (int f = 0; f < 32; ++f) acc[f] = 0.f;
#pragma unroll
    for (int j = 0; j < 16; ++j)
#pragma unroll
        for (int f = 0; f < 32; ++f) acc[f] += hr[j] * sW[j * 32 + f];
#pragma unroll
    for (int q = 0; q < 8; ++q) {
        float4 r = make_float4(acc[q * 4 + 0], acc[q * 4 + 1], acc[q * 4 + 2], acc[q * 4 + 3]);
        *reinterpret_cast<float4*>(&o[n * 32 + q * 4]) = r;
    }
}

// -------- kernels 2 & 4: H = relu(A @ P + b), barrier-free per-wave pipeline -
// Block = 256 thr = 4 independent waves; wave stages ITS OWN 8 rows (1KB
// contiguous burst per row via global_load_lds w16) into its own LDS region
// and is the only consumer -> NO __syncthreads. Per tile: vmcnt(0) rendezvous
// (stage issued one tile ago), preload ALL P for the tile to regs (issued
// before next stage so counted P-waits never retire it), issue stage(k+1),
// compute from LDS (2-way bank conflicts = free). Epilogue: shfl_xor reduce
// over the 16 k-groups + bias + relu.
template <int F>
__global__ __launch_bounds__(256, 2) void k_spmm(
    const float* __restrict__ A0, const float* __restrict__ A1,
    const float* __restrict__ Pm0, const float* __restrict__ Pm1,
    const float* __restrict__ b0, const float* __restrict__ b1,
    float* __restrict__ o0, float* __restrict__ o1, int ostride) {
    constexpr int TN = F / 4;   // cols per thread: 8 (F=32) or 4 (F=16)
    constexpr int PJ = TN / 4;  // float4s of P per k: 2 or 1
    constexpr int KT = 256;     // k-tile; 1KB per row per stage instruction
    constexpr int NT = N / KT;  // 32 tiles
    const int branch = blockIdx.y;
    const float* __restrict__ A = branch ? A1 : A0;
    const float* __restrict__ Pm = branch ? Pm1 : Pm0;
    const float* __restrict__ bias = branch ? b1 : b0;
    float* __restrict__ o = branch ? o1 : o0;

    __shared__ float tile[2][32 * KT];  // 64 KB -> 2 blocks/CU

    const int lane = threadIdx.x & 63;
    const int wave = threadIdx.x >> 6;
    const int kg = lane & 15;  // k-group within wave
    const int cg = lane >> 4;  // col-group 0..3
    const int c0 = cg * TN;
    const int row0 = blockIdx.x * 32;
    const float* gsrc = A + (size_t)(row0 + wave * 8) * N + lane * 4;

    auto stage = [&](int buf, int K0) {
#pragma unroll
        for (int r = 0; r < 8; ++r)
            gload_lds16(gsrc + (size_t)r * N + K0, &tile[buf][(wave * 8 + r) * KT]);
    };

    float acc[8][TN];
#pragma unroll
    for (int m = 0; m < 8; ++m)
#pragma unroll
        for (int j = 0; j < TN; ++j) acc[m][j] = 0.f;

    stage(0, 0);

    for (int it = 0; it < NT; ++it) {
        const int K0 = it * KT;
        const int buf = it & 1;
        // rendezvous: only stage(it) outstanding, issued one full tile ago
        asm volatile("s_waitcnt vmcnt(0)" ::: "memory");
        __builtin_amdgcn_sched_barrier(0);
        // preload ALL P for this tile (before next stage -> no forced retire)
        float4 p[4][4][PJ];
#pragma unroll
        for (int ks = 0; ks < 4; ++ks)
#pragma unroll
            for (int t = 0; t < 4; ++t)
#pragma unroll
                for (int j = 0; j < PJ; ++j)
                    p[ks][t][j] = *reinterpret_cast<const float4*>(
                        Pm + (size_t)(K0 + ks * 64 + kg * 4 + t) * F + c0 + j * 4);
        __builtin_amdgcn_sched_barrier(0);
        if (it + 1 < NT) stage(buf ^ 1, K0 + KT);
        __builtin_amdgcn_sched_barrier(0);
        // compute from LDS; overlaps stage(it+1) HBM delivery
#pragma unroll
        for (int ks = 0; ks < 4; ++ks) {
            const int kk = ks * 64 + kg * 4;
#pragma unroll
            for (int m = 0; m < 8; ++m) {
                const float4 a = *reinterpret_cast<const float4*>(
                    &tile[buf][(wave * 8 + m) * KT + kk]);
#pragma unroll
                for (int t = 0; t < 4; ++t) {
                    const float av = (t == 0) ? a.x : (t == 1) ? a.y : (t == 2) ? a.z : a.w;
#pragma unroll
                    for (int j = 0; j < PJ; ++j) {
                        acc[m][j * 4 + 0] += av * p[ks][t][j].x;
                        acc[m][j * 4 + 1] += av * p[ks][t][j].y;
                        acc[m][j * 4 + 2] += av * p[ks][t][j].z;
                        acc[m][j * 4 + 3] += av * p[ks][t][j].w;
                    }
                }
            }
        }
    }

    // reduce across the 16 k-groups
#pragma unroll
    for (int m = 0; m < 8; ++m)
#pragma unroll
        for (int j = 0; j < TN; ++j) {
            float v = acc[m][j];
            v += __shfl_xor(v, 1);
            v += __shfl_xor(v, 2);
            v += __shfl_xor(v, 4);
            v += __shfl_xor(v, 8);
            acc[m][j] = v;
        }
    if (kg == 0) {
#pragma unroll
        for (int m = 0; m < 8; ++m)
#pragma unroll
            for (int j = 0; j < PJ; ++j) {
                float4 r;
                r.x = fmaxf(acc[m][j * 4 + 0] + bias[c0 + j * 4 + 0], 0.f);
                r.y = fmaxf(acc[m][j * 4 + 1] + bias[c0 + j * 4 + 1], 0.f);
                r.z = fmaxf(acc[m][j * 4 + 2] + bias[c0 + j * 4 + 2], 0.f);
                r.w = fmaxf(acc[m][j * 4 + 3] + bias[c0 + j * 4 + 3], 0.f);
                *reinterpret_cast<float4*>(
                    &o[(size_t)(row0 + wave * 8 + m) * ostride + c0 + j * 4]) = r;
            }
    }
}

// ------- kernel 5: per-block partials of Z_h = sum e^{s}, U_h = sum e^{s}(h.Wd_h)
// tanh in [-1,1] -> softmax without max-subtraction is safe.
__global__ void k_att_pool(const float* __restrict__ h, const float* __restrict__ Watt,
                           const float* __restrict__ Wd, float* __restrict__ partials) {
    __shared__ float sWa[64 * 3];
    __shared__ float sWd[192];
    for (int i = threadIdx.x; i < 192; i += blockDim.x) {
        sWa[i] = Watt[i];
        sWd[i] = Wd[i];
    }
    __syncthreads();
    const int n = blockIdx.x * blockDim.x + threadIdx.x;  // 32*256 == N exactly
    float hv[64];
#pragma unroll
    for (int q = 0; q < 16; ++q)
        *reinterpret_cast<float4*>(&hv[q * 4]) =
            *reinterpret_cast<const float4*>(&h[(size_t)n * 64 + q * 4]);
    float s0 = 0.f, s1 = 0.f, s2 = 0.f;
#pragma unroll
    for (int d = 0; d < 64; ++d) {
        s0 += hv[d] * sWa[d * 3 + 0];
        s1 += hv[d] * sWa[d * 3 + 1];
        s2 += hv[d] * sWa[d * 3 + 2];
    }
    float dot0 = 0.f, dot1 = 0.f, dot2 = 0.f;
#pragma unroll
    for (int d = 0; d < 64; ++d) {
        dot0 += hv[d] * sWd[0 * 64 + d];
        dot1 += hv[d] * sWd[1 * 64 + d];
        dot2 += hv[d] * sWd[2 * 64 + d];
    }
    const float e0 = expf(tanhf(s0));
    const float e1 = expf(tanhf(s1));
    const float e2 = expf(tanhf(s2));
    float vals[6] = {e0, e1, e2, e0 * dot0, e1 * dot1, e2 * dot2};
#pragma unroll
    for (int i = 0; i < 6; ++i) {
        float v = vals[i];
#pragma unroll
        for (int off = 1; off < 64; off <<= 1) v += __shfl_xor(v, off);
        vals[i] = v;
    }
    __shared__ float sred[4][6];
    const int wave = threadIdx.x >> 6, lane = threadIdx.x & 63;
    if (lane == 0) {
#pragma unroll
        for (int i = 0; i < 6; ++i) sred[wave][i] = vals[i];
    }
    __syncthreads();
    if (threadIdx.x == 0) {
#pragma unroll
        for (int i = 0; i < 6; ++i)
            partials[blockIdx.x * 6 + i] = sred[0][i] + sred[1][i] + sred[2][i] + sred[3][i];
    }
}

// ------------- kernel 6: out = sum_h U_h/Z_h + b_dense -------------
__global__ void k_att_final(const float* __restrict__ partials, const float* __restrict__ bd,
                            float* __restrict__ out) {
    if (threadIdx.x == 0) {
        float Z0 = 0.f, Z1 = 0.f, Z2 = 0.f, U0 = 0.f, U1 = 0.f, U2 = 0.f;
        for (int b = 0; b < 32; ++b) {
            Z0 += partials[b * 6 + 0];
            Z1 += partials[b * 6 + 1];
            Z2 += partials[b * 6 + 2];
            U0 += partials[b * 6 + 3];
            U1 += partials[b * 6 + 4];
            U2 += partials[b * 6 + 5];
        }
        out[0] = U0 / Z0 + U1 / Z1 + U2 / Z2 + bd[0];
    }
}

extern "C" void kernel_launch(void* const* d_in, const int* in_sizes, int n_in,
                              void* d_out, int out_size, void* d_ws, size_t ws_size,
                              hipStream_t stream) {
    const float* x_int   = (const float*)d_in[0];
    const float* x_nh    = (const float*)d_in[1];
    const float* adj_int = (const float*)d_in[2];
    const float* adj_nh  = (const float*)d_in[3];
    const float* W1_int  = (const float*)d_in[4];
    const float* b1_int  = (const float*)d_in[5];
    const float* W1_nh   = (const float*)d_in[6];
    const float* b1_nh   = (const float*)d_in[7];
    const float* W2_int  = (const float*)d_in[8];
    const float* b2_int  = (const float*)d_in[9];
    const float* W2_nh   = (const float*)d_in[10];
    const float* b2_nh   = (const float*)d_in[11];
    const float* W_att   = (const float*)d_in[12];
    const float* W_dense = (const float*)d_in[13];
    const float* b_dense = (const float*)d_in[14];

    float* ws = (float*)d_ws;
    float* P1_0 = ws;                        // [8192,16]
    float* P1_1 = ws + 131072;
    float* H1_0 = ws + 262144;               // [8192,16]
    float* H1_1 = ws + 393216;
    float* P2_0 = ws + 524288;               // [8192,32]
    float* P2_1 = ws + 786432;
    float* hcat = ws + 1048576;              // [8192,64] = [H2_int | H2_nh]
    float* partials = ws + 1572864;          // [32,6]
    float* out = (float*)d_out;

    k_dense_in<<<dim3(32, 2), 256, 0, stream>>>(x_int, x_nh, W1_int, W1_nh, P1_0, P1_1);
    k_spmm<16><<<dim3(256, 2), 256, 0, stream>>>(adj_int, adj_nh, P1_0, P1_1,
                                                 b1_int, b1_nh, H1_0, H1_1, 16);
    k_dense_mid<<<dim3(32, 2), 256, 0, stream>>>(H1_0, H1_1, W2_int, W2_nh, P2_0, P2_1);
    k_spmm<32><<<dim3(256, 2), 256, 0, stream>>>(adj_int, adj_nh, P2_0, P2_1,
                                                 b2_int, b2_nh, hcat, hcat + 32, 64);
    k_att_pool<<<32, 256, 0, stream>>>(hcat, W_att, W_dense, partials);
    k_att_final<<<1, 64, 0, stream>>>(partials, b_dense, out);
}

// Round 4
// 506.106 us; speedup vs baseline: 1.0431x; 1.0431x over previous
//
#include <hip/hip_runtime.h>

// GNN27: two-branch diffusion GCN (N=8192, F_IN=11, F1=16, F2=32) + multi-head
// tanh-attention pooling. All fp32. Memory-bound on the two 268MB adjacencies,
// each streamed twice (layer1, layer2) -> 1.07GB HBM floor ~170us.
//
// R1: 256B-granular loads -> 680 GB/s. R2: LDS staging -> 955 GB/s.
// R3: barrier-free per-wave pipeline -> no change (sync wasn't the wall).
// Diagnosis: A's row stride is exactly 32KB; all waves progress through K in
// phase, so the chip's instantaneous fetch set is congruent mod 32KB ->
// channel/bank subset hammering. R4: per-wave K-phase rotation (wave g visits
// K-tiles in order (t+g) mod NT) -> instantaneous address set covers all
// offset classes uniformly. Also: F=32 uses KT=128 so the per-tile P preload
// fits in registers (R3's 128-reg P array spilled).

constexpr int N = 8192;

#define GLOBAL_AS __attribute__((address_space(1)))
#define LDS_AS __attribute__((address_space(3)))

__device__ __forceinline__ void gload_lds16(const float* g, float* l) {
    __builtin_amdgcn_global_load_lds((const GLOBAL_AS void*)g, (LDS_AS void*)l, 16, 0, 0);
}

// ---------------- kernel 1: P1 = x @ W1   ([N,11] @ [11,16]) ----------------
__global__ void k_dense_in(const float* __restrict__ x0, const float* __restrict__ x1,
                           const float* __restrict__ W0, const float* __restrict__ W1,
                           float* __restrict__ o0, float* __restrict__ o1) {
    const int branch = blockIdx.y;
    const float* __restrict__ x = branch ? x1 : x0;
    const float* __restrict__ W = branch ? W1 : W0;
    float* __restrict__ o = branch ? o1 : o0;
    __shared__ float sW[11 * 16];
    if (threadIdx.x < 176) sW[threadIdx.x] = W[threadIdx.x];
    __syncthreads();
    const int n = blockIdx.x * blockDim.x + threadIdx.x;  // grid.x*256 == N exactly
    float xr[11];
#pragma unroll
    for (int j = 0; j < 11; ++j) xr[j] = x[n * 11 + j];
    float acc[16];
#pragma unroll
    for (int f = 0; f < 16; ++f) acc[f] = 0.f;
#pragma unroll
    for (int j = 0; j < 11; ++j)
#pragma unroll
        for (int f = 0; f < 16; ++f) acc[f] += xr[j] * sW[j * 16 + f];
#pragma unroll
    for (int q = 0; q < 4; ++q) {
        float4 r = make_float4(acc[q * 4 + 0], acc[q * 4 + 1], acc[q * 4 + 2], acc[q * 4 + 3]);
        *reinterpret_cast<float4*>(&o[n * 16 + q * 4]) = r;
    }
}

// ---------------- kernel 3: P2 = H1 @ W2   ([N,16] @ [16,32]) ----------------
__global__ void k_dense_mid(const float* __restrict__ h0, const float* __restrict__ h1,
                            const float* __restrict__ W0, const float* __restrict__ W1,
                            float* __restrict__ o0, float* __restrict__ o1) {
    const int branch = blockIdx.y;
    const float* __restrict__ h = branch ? h1 : h0;
    const float* __restrict__ W = branch ? W1 : W0;
    float* __restrict__ o = branch ? o1 : o0;
    __shared__ float sW[16 * 32];
    for (int i = threadIdx.x; i < 512; i += blockDim.x) sW[i] = W[i];
    __syncthreads();
    const int n = blockIdx.x * blockDim.x + threadIdx.x;
    float hr[16];
#pragma unroll
    for (int q = 0; q < 4; ++q)
        *reinterpret_cast<float4*>(&hr[q * 4]) =
            *reinterpret_cast<const float4*>(&h[n * 16 + q * 4]);
    float acc[32];
#pragma unroll
    for (int f = 0; f < 32; ++f) acc[f] = 0.f;
#pragma unroll
    for (int j = 0; j < 16; ++j)
#pragma unroll
        for (int f = 0; f < 32; ++f) acc[f] += hr[j] * sW[j * 32 + f];
#pragma unroll
    for (int q = 0; q < 8; ++q) {
        float4 r = make_float4(acc[q * 4 + 0], acc[q * 4 + 1], acc[q * 4 + 2], acc[q * 4 + 3]);
        *reinterpret_cast<float4*>(&o[n * 32 + q * 4]) = r;
    }
}

// -------- kernels 2 & 4: H = relu(A @ P + b), per-wave pipeline + K-rotation -
// Block = 4 independent waves; wave stages ITS OWN 8 rows into its own LDS
// region (no __syncthreads). Wave with global id g visits K-tiles in order
// (t+g)&(NT-1): breaks the 32KB-congruent chip-wide fetch pattern. Per tile:
// vmcnt(0) rendezvous (stage issued one tile ago) -> preload ALL P for this
// tile to regs (before next stage, so counted P-waits never retire it) ->
// issue stage(next) -> compute from LDS.
template <int F, int KT>
__global__ __launch_bounds__(256, 2) void k_spmm(
    const float* __restrict__ A0, const float* __restrict__ A1,
    const float* __restrict__ Pm0, const float* __restrict__ Pm1,
    const float* __restrict__ b0, const float* __restrict__ b1,
    float* __restrict__ o0, float* __restrict__ o1, int ostride) {
    constexpr int TN = F / 4;    // cols per thread: 8 (F=32) or 4 (F=16)
    constexpr int PJ = TN / 4;   // float4s of P per k: 2 or 1
    constexpr int NT = N / KT;   // tiles
    constexpr int KS = KT / 64;  // k-subtiles per tile
    const int branch = blockIdx.y;
    const float* __restrict__ A = branch ? A1 : A0;
    const float* __restrict__ Pm = branch ? Pm1 : Pm0;
    const float* __restrict__ bias = branch ? b1 : b0;
    float* __restrict__ o = branch ? o1 : o0;

    __shared__ float tile[2][32 * KT];

    const int lane = threadIdx.x & 63;
    const int wave = threadIdx.x >> 6;
    const int kg = lane & 15;  // k-group within wave
    const int cg = lane >> 4;  // col-group 0..3
    const int c0 = cg * TN;
    const int row0 = blockIdx.x * 32;
    const int phase = (blockIdx.x * 4 + wave) & (NT - 1);  // K-rotation

    // staging source: one gload_lds covers 1KB = 1024/(KT*4) rows
    const float* gsrc;
    if constexpr (KT == 256) {
        gsrc = A + (size_t)(row0 + wave * 8) * N + lane * 4;
    } else {  // KT == 128: lanes 0-31 -> row 2i, lanes 32-63 -> row 2i+1
        gsrc = A + (size_t)(row0 + wave * 8 + (lane >> 5)) * N + (lane & 31) * 4;
    }

    auto stage = [&](int buf, int K0) {
        if constexpr (KT == 256) {
#pragma unroll
            for (int r = 0; r < 8; ++r)
                gload_lds16(gsrc + (size_t)r * N + K0, &tile[buf][(wave * 8 + r) * KT]);
        } else {
#pragma unroll
            for (int i = 0; i < 4; ++i)
                gload_lds16(gsrc + (size_t)(2 * i) * N + K0,
                            &tile[buf][(wave * 8 + 2 * i) * KT]);
        }
    };

    float acc[8][TN];
#pragma unroll
    for (int m = 0; m < 8; ++m)
#pragma unroll
        for (int j = 0; j < TN; ++j) acc[m][j] = 0.f;

    stage(0, phase * KT);

    for (int it = 0; it < NT; ++it) {
        const int K0 = ((it + phase) & (NT - 1)) * KT;
        const int buf = it & 1;
        // rendezvous: only stage(it) outstanding, issued one full tile ago
        asm volatile("s_waitcnt vmcnt(0)" ::: "memory");
        __builtin_amdgcn_sched_barrier(0);
        // preload ALL P for this tile (before next stage -> no forced retire)
        float4 p[KS][4][PJ];
#pragma unroll
        for (int ks = 0; ks < KS; ++ks)
#pragma unroll
            for (int t = 0; t < 4; ++t)
#pragma unroll
                for (int j = 0; j < PJ; ++j)
                    p[ks][t][j] = *reinterpret_cast<const float4*>(
                        Pm + (size_t)(K0 + ks * 64 + kg * 4 + t) * F + c0 + j * 4);
        __builtin_amdgcn_sched_barrier(0);
        if (it + 1 < NT) stage(buf ^ 1, ((it + 1 + phase) & (NT - 1)) * KT);
        __builtin_amdgcn_sched_barrier(0);
        // compute from LDS; overlaps stage(it+1) HBM delivery
#pragma unroll
        for (int ks = 0; ks < KS; ++ks) {
            const int kk = ks * 64 + kg * 4;
#pragma unroll
            for (int m = 0; m < 8; ++m) {
                const float4 a = *reinterpret_cast<const float4*>(
                    &tile[buf][(wave * 8 + m) * KT + kk]);
#pragma unroll
                for (int t = 0; t < 4; ++t) {
                    const float av = (t == 0) ? a.x : (t == 1) ? a.y : (t == 2) ? a.z : a.w;
#pragma unroll
                    for (int j = 0; j < PJ; ++j) {
                        acc[m][j * 4 + 0] += av * p[ks][t][j].x;
                        acc[m][j * 4 + 1] += av * p[ks][t][j].y;
                        acc[m][j * 4 + 2] += av * p[ks][t][j].z;
                        acc[m][j * 4 + 3] += av * p[ks][t][j].w;
                    }
                }
            }
        }
    }

    // reduce across the 16 k-groups
#pragma unroll
    for (int m = 0; m < 8; ++m)
#pragma unroll
        for (int j = 0; j < TN; ++j) {
            float v = acc[m][j];
            v += __shfl_xor(v, 1);
            v += __shfl_xor(v, 2);
            v += __shfl_xor(v, 4);
            v += __shfl_xor(v, 8);
            acc[m][j] = v;
        }
    if (kg == 0) {
#pragma unroll
        for (int m = 0; m < 8; ++m)
#pragma unroll
            for (int j = 0; j < PJ; ++j) {
                float4 r;
                r.x = fmaxf(acc[m][j * 4 + 0] + bias[c0 + j * 4 + 0], 0.f);
                r.y = fmaxf(acc[m][j * 4 + 1] + bias[c0 + j * 4 + 1], 0.f);
                r.z = fmaxf(acc[m][j * 4 + 2] + bias[c0 + j * 4 + 2], 0.f);
                r.w = fmaxf(acc[m][j * 4 + 3] + bias[c0 + j * 4 + 3], 0.f);
                *reinterpret_cast<float4*>(
                    &o[(size_t)(row0 + wave * 8 + m) * ostride + c0 + j * 4]) = r;
            }
    }
}

// ------- kernel 5: per-block partials of Z_h = sum e^{s}, U_h = sum e^{s}(h.Wd_h)
// tanh in [-1,1] -> softmax without max-subtraction is safe.
__global__ void k_att_pool(const float* __restrict__ h, const float* __restrict__ Watt,
                           const float* __restrict__ Wd, float* __restrict__ partials) {
    __shared__ float sWa[64 * 3];
    __shared__ float sWd[192];
    for (int i = threadIdx.x; i < 192; i += blockDim.x) {
        sWa[i] = Watt[i];
        sWd[i] = Wd[i];
    }
    __syncthreads();
    const int n = blockIdx.x * blockDim.x + threadIdx.x;  // 32*256 == N exactly
    float hv[64];
#pragma unroll
    for (int q = 0; q < 16; ++q)
        *reinterpret_cast<float4*>(&hv[q * 4]) =
            *reinterpret_cast<const float4*>(&h[(size_t)n * 64 + q * 4]);
    float s0 = 0.f, s1 = 0.f, s2 = 0.f;
#pragma unroll
    for (int d = 0; d < 64; ++d) {
        s0 += hv[d] * sWa[d * 3 + 0];
        s1 += hv[d] * sWa[d * 3 + 1];
        s2 += hv[d] * sWa[d * 3 + 2];
    }
    float dot0 = 0.f, dot1 = 0.f, dot2 = 0.f;
#pragma unroll
    for (int d = 0; d < 64; ++d) {
        dot0 += hv[d] * sWd[0 * 64 + d];
        dot1 += hv[d] * sWd[1 * 64 + d];
        dot2 += hv[d] * sWd[2 * 64 + d];
    }
    const float e0 = expf(tanhf(s0));
    const float e1 = expf(tanhf(s1));
    const float e2 = expf(tanhf(s2));
    float vals[6] = {e0, e1, e2, e0 * dot0, e1 * dot1, e2 * dot2};
#pragma unroll
    for (int i = 0; i < 6; ++i) {
        float v = vals[i];
#pragma unroll
        for (int off = 1; off < 64; off <<= 1) v += __shfl_xor(v, off);
        vals[i] = v;
    }
    __shared__ float sred[4][6];
    const int wave = threadIdx.x >> 6, lane = threadIdx.x & 63;
    if (lane == 0) {
#pragma unroll
        for (int i = 0; i < 6; ++i) sred[wave][i] = vals[i];
    }
    __syncthreads();
    if (threadIdx.x == 0) {
#pragma unroll
        for (int i = 0; i < 6; ++i)
            partials[blockIdx.x * 6 + i] = sred[0][i] + sred[1][i] + sred[2][i] + sred[3][i];
    }
}

// ------------- kernel 6: out = sum_h U_h/Z_h + b_dense -------------
__global__ void k_att_final(const float* __restrict__ partials, const float* __restrict__ bd,
                            float* __restrict__ out) {
    if (threadIdx.x == 0) {
        float Z0 = 0.f, Z1 = 0.f, Z2 = 0.f, U0 = 0.f, U1 = 0.f, U2 = 0.f;
        for (int b = 0; b < 32; ++b) {
            Z0 += partials[b * 6 + 0];
            Z1 += partials[b * 6 + 1];
            Z2 += partials[b * 6 + 2];
            U0 += partials[b * 6 + 3];
            U1 += partials[b * 6 + 4];
            U2 += partials[b * 6 + 5];
        }
        out[0] = U0 / Z0 + U1 / Z1 + U2 / Z2 + bd[0];
    }
}

extern "C" void kernel_launch(void* const* d_in, const int* in_sizes, int n_in,
                              void* d_out, int out_size, void* d_ws, size_t ws_size,
                              hipStream_t stream) {
    const float* x_int   = (const float*)d_in[0];
    const float* x_nh    = (const float*)d_in[1];
    const float* adj_int = (const float*)d_in[2];
    const float* adj_nh  = (const float*)d_in[3];
    const float* W1_int  = (const float*)d_in[4];
    const float* b1_int  = (const float*)d_in[5];
    const float* W1_nh   = (const float*)d_in[6];
    const float* b1_nh   = (const float*)d_in[7];
    const float* W2_int  = (const float*)d_in[8];
    const float* b2_int  = (const float*)d_in[9];
    const float* W2_nh   = (const float*)d_in[10];
    const float* b2_nh   = (const float*)d_in[11];
    const float* W_att   = (const float*)d_in[12];
    const float* W_dense = (const float*)d_in[13];
    const float* b_dense = (const float*)d_in[14];

    float* ws = (float*)d_ws;
    float* P1_0 = ws;                        // [8192,16]
    float* P1_1 = ws + 131072;
    float* H1_0 = ws + 262144;               // [8192,16]
    float* H1_1 = ws + 393216;
    float* P2_0 = ws + 524288;               // [8192,32]
    float* P2_1 = ws + 786432;
    float* hcat = ws + 1048576;              // [8192,64] = [H2_int | H2_nh]
    float* partials = ws + 1572864;          // [32,6]
    float* out = (float*)d_out;

    k_dense_in<<<dim3(32, 2), 256, 0, stream>>>(x_int, x_nh, W1_int, W1_nh, P1_0, P1_1);
    k_spmm<16, 256><<<dim3(256, 2), 256, 0, stream>>>(adj_int, adj_nh, P1_0, P1_1,
                                                      b1_int, b1_nh, H1_0, H1_1, 16);
    k_dense_mid<<<dim3(32, 2), 256, 0, stream>>>(H1_0, H1_1, W2_int, W2_nh, P2_0, P2_1);
    k_spmm<32, 128><<<dim3(256, 2), 256, 0, stream>>>(adj_int, adj_nh, P2_0, P2_1,
                                                      b2_int, b2_nh, hcat, hcat + 32, 64);
    k_att_pool<<<32, 256, 0, stream>>>(hcat, W_att, W_dense, partials);
    k_att_final<<<1, 64, 0, stream>>>(partials, b_dense, out);
}